// Round 1
// 411.793 us; speedup vs baseline: 1.0661x; 1.0661x over previous
//
#include <hip/hip_runtime.h>
#include <cstdint>

constexpr int NCOLS   = 4096;
constexpr int THREADS = 256;
constexpr int EPT     = NCOLS / THREADS;  // 16 elements per thread
constexpr int KSEL    = 65;               // need 65th largest (and 64th)
constexpr uint32_t TPAT = 0x40000000u;    // bit pattern of 2.0f (prefilter threshold)
constexpr int CAP     = 256;              // max candidates for fast path (4 per lane of wave 0)

typedef float f32x4 __attribute__((ext_vector_type(4)));

// Soft-threshold preserving sign.
__device__ __forceinline__ float soft(float x, float Q) {
    float r = fmaxf(fabsf(x) - Q, 0.0f);
    return copysignf(r, x);
}

__global__ __launch_bounds__(THREADS) void topk_sparsify(
    const float* __restrict__ X, float* __restrict__ out, int rows)
{
    const int row = blockIdx.x;
    if (row >= rows) return;
    const int t    = threadIdx.x;
    const int lane = t & 63;
    const int wave = t >> 6;

    const f32x4* __restrict__ x4 = reinterpret_cast<const f32x4*>(X + (size_t)row * NCOLS);
    f32x4* __restrict__       o4 = reinterpret_cast<f32x4*>(out + (size_t)row * NCOLS);

    // ---- Load row: 4 float4 per thread, coalesced; nontemporal (single-use stream)
    f32x4 d[4];
#pragma unroll
    for (int i = 0; i < 4; ++i) d[i] = __builtin_nontemporal_load(x4 + t + THREADS * i);

    // abs bit patterns (unsigned compare == float compare for non-negative)
    uint32_t a[EPT];
#pragma unroll
    for (int i = 0; i < 4; ++i) {
#pragma unroll
        for (int j = 0; j < 4; ++j)
            a[4 * i + j] = __float_as_uint(d[i][j]) & 0x7FFFFFFFu;
    }

    __shared__ uint32_t list[CAP];   // compacted candidate patterns
    __shared__ uint32_t wtot[4];
    __shared__ uint32_t wcnt[4], wmn[4];
    __shared__ uint32_t b65_s;
    __shared__ float    q_sh;

    // ---- Prefilter: count |x| > 2.0 candidates, block-compact them into LDS.
    uint32_t cnt = 0;
#pragma unroll
    for (int i = 0; i < EPT; ++i) cnt += (a[i] > TPAT) ? 1u : 0u;

    // wave-level inclusive prefix sum of per-thread counts
    uint32_t inc = cnt;
#pragma unroll
    for (int off = 1; off < 64; off <<= 1) {
        uint32_t v = __shfl_up(inc, off, 64);
        if (lane >= off) inc += v;
    }
    if (lane == 63) wtot[wave] = inc;
    __syncthreads();

    uint32_t C = 0, base = 0;
#pragma unroll
    for (int w = 0; w < 4; ++w) {
        uint32_t tw = wtot[w];
        C += tw;
        if (w < wave) base += tw;
    }
    const bool fast = (C >= (uint32_t)KSEL) && (C <= (uint32_t)CAP);  // block-uniform

    if (fast) {
        uint32_t o = base + inc - cnt;   // exclusive global offset
#pragma unroll
        for (int i = 0; i < EPT; ++i)
            if (a[i] > TPAT) list[o++] = a[i];
    }
    __syncthreads();

    // ---- Exact bitwise radix-select of the 65th largest
    uint32_t b65;
    if (fast) {
        // Wave 0 only: candidates in registers (<=4/lane), ballot-count per bit.
        if (t < 64) {
            const uint32_t c0 = ((uint32_t)t        < C) ? list[t]        : 0u;
            const uint32_t c1 = ((uint32_t)t + 64u  < C) ? list[t + 64]   : 0u;
            const uint32_t c2 = ((uint32_t)t + 128u < C) ? list[t + 128]  : 0u;
            const uint32_t c3 = ((uint32_t)t + 192u < C) ? list[t + 192]  : 0u;
            uint32_t prefix = 0, kk = KSEL;
            for (int b = 30; b >= 0; --b) {
                const uint32_t want = prefix | (1u << b);        // has bit b set -> pad 0 never matches
                const uint32_t mhi  = ~((1u << b) - 1u);
                uint64_t m0 = __ballot((c0 & mhi) == want);
                uint64_t m1 = __ballot((c1 & mhi) == want);
                uint64_t m2 = __ballot((c2 & mhi) == want);
                uint64_t m3 = __ballot((c3 & mhi) == want);
                const uint32_t cc = (uint32_t)(__popcll(m0) + __popcll(m1) +
                                               __popcll(m2) + __popcll(m3));
                if (cc >= kk) prefix = want; else kk -= cc;
            }
            if (t == 0) b65_s = prefix;
        }
        __syncthreads();
        b65 = b65_s;
    } else {
        // Fallback (adversarial data only): exact block-wide bitwise select over all elements.
        uint32_t prefix = 0, kk = KSEL;
        for (int b = 30; b >= 0; --b) {
            const uint32_t want = prefix | (1u << b);
            const uint32_t mhi  = ~((1u << b) - 1u);
            uint32_t c = 0;
#pragma unroll
            for (int i = 0; i < EPT; ++i) c += ((a[i] & mhi) == want) ? 1u : 0u;
#pragma unroll
            for (int off2 = 32; off2 >= 1; off2 >>= 1) c += __shfl_down(c, off2, 64);
            if (lane == 0) wcnt[wave] = c;
            __syncthreads();
            const uint32_t tot = wcnt[0] + wcnt[1] + wcnt[2] + wcnt[3];
            if (tot >= kk) prefix = want; else kk -= tot;
            __syncthreads();
        }
        b65 = prefix;
    }
    const float v65 = __uint_as_float(b65);

    // ---- 64th largest: min of elements strictly > b65 (if exactly 64 exist)
    uint32_t cgt = 0, mn = 0xFFFFFFFFu;
#pragma unroll
    for (int i = 0; i < EPT; ++i) {
        if (a[i] > b65) { cgt++; mn = min(mn, a[i]); }
    }
#pragma unroll
    for (int off2 = 32; off2 >= 1; off2 >>= 1) {
        cgt += __shfl_down(cgt, off2, 64);
        uint32_t m2 = __shfl_down(mn, off2, 64);
        mn = min(mn, m2);
    }
    if (lane == 0) { wcnt[wave] = cgt; wmn[wave] = mn; }
    __syncthreads();
    if (t == 0) {
        const uint32_t Ct = wcnt[0] + wcnt[1] + wcnt[2] + wcnt[3];
        const uint32_t M  = min(min(wmn[0], wmn[1]), min(wmn[2], wmn[3]));
        const float v64 = (Ct == 64u) ? __uint_as_float(M) : v65;
        // Q = v65 + frac*(v64 - v65), frac = 1/64 (exact in binary)
        q_sh = fmaf(0.015625f, v64 - v65, v65);
    }
    __syncthreads();
    const float Q = q_sh;

    // ---- write output, coalesced float4, nontemporal (streaming)
#pragma unroll
    for (int i = 0; i < 4; ++i) {
        f32x4 f;
#pragma unroll
        for (int j = 0; j < 4; ++j) f[j] = soft(d[i][j], Q);
        __builtin_nontemporal_store(f, o4 + t + THREADS * i);
    }
}

extern "C" void kernel_launch(void* const* d_in, const int* in_sizes, int n_in,
                              void* d_out, int out_size, void* d_ws, size_t ws_size,
                              hipStream_t stream) {
    const float* X   = (const float*)d_in[0];
    float*       out = (float*)d_out;
    const int rows = in_sizes[0] / NCOLS;   // 16384
    topk_sparsify<<<rows, THREADS, 0, stream>>>(X, out, rows);
}

// Round 2
// 410.574 us; speedup vs baseline: 1.0692x; 1.0030x over previous
//
#include <hip/hip_runtime.h>
#include <cstdint>

constexpr int NCOLS   = 4096;
constexpr int THREADS = 256;
constexpr int EPT     = NCOLS / THREADS;  // 16 elements per thread
constexpr int KSEL    = 65;               // need 65th largest (and 64th)
constexpr uint32_t TPAT = 0x40000000u;    // bit pattern of 2.0f (prefilter threshold)
constexpr int CAP     = 256;              // max candidates for fast path (4 per lane of wave 0)

typedef float f32x4 __attribute__((ext_vector_type(4)));

__global__ __launch_bounds__(THREADS, 8) void topk_sparsify(
    const float* __restrict__ X, float* __restrict__ out, int rows)
{
    const int row = blockIdx.x;
    if (row >= rows) return;
    const int t    = threadIdx.x;
    const int lane = t & 63;
    const int wave = t >> 6;

    const f32x4* __restrict__ x4 = reinterpret_cast<const f32x4*>(X + (size_t)row * NCOLS);

    // ---- Load row (coalesced, nontemporal). Keep only abs patterns + packed sign bits.
    uint32_t a[EPT];        // abs bit patterns (unsigned cmp == float cmp for non-neg)
    uint32_t smask = 0;     // bit e = sign bit of element e
#pragma unroll
    for (int i = 0; i < 4; ++i) {
        f32x4 v = __builtin_nontemporal_load(x4 + t + THREADS * i);
#pragma unroll
        for (int j = 0; j < 4; ++j) {
            const uint32_t p = __float_as_uint(v[j]);
            smask |= (p >> 31) << (4 * i + j);
            a[4 * i + j] = p & 0x7FFFFFFFu;
        }
    }

    __shared__ uint32_t list[CAP];   // compacted candidate patterns
    __shared__ uint32_t wtot[4];
    __shared__ uint32_t wcnt[4], wmn[4];   // fallback only
    __shared__ float    q_sh;

    // ---- Prefilter: count |x| > 2.0 candidates, block-compact them into LDS.
    uint32_t cnt = 0;
#pragma unroll
    for (int i = 0; i < EPT; ++i) cnt += (a[i] > TPAT) ? 1u : 0u;

    // wave-level inclusive prefix sum of per-thread counts
    uint32_t inc = cnt;
#pragma unroll
    for (int off = 1; off < 64; off <<= 1) {
        uint32_t v = __shfl_up(inc, off, 64);
        if (lane >= off) inc += v;
    }
    if (lane == 63) wtot[wave] = inc;
    __syncthreads();

    uint32_t C = 0, base = 0;
#pragma unroll
    for (int w = 0; w < 4; ++w) {
        const uint32_t tw = wtot[w];
        C += tw;
        if (w < wave) base += tw;
    }
    const bool fast = (C >= (uint32_t)KSEL) && (C <= (uint32_t)CAP);  // block-uniform

    if (fast) {
        uint32_t o = base + inc - cnt;   // exclusive global offset
#pragma unroll
        for (int i = 0; i < EPT; ++i)
            if (a[i] > TPAT) list[o++] = a[i];
        __syncthreads();

        // ---- Wave 0 alone: exact radix-select of 65th largest AND the 64th,
        // entirely over its 4 candidate registers (b65 > TPAT, so every
        // element > b65 is in the candidate list).
        if (t < 64) {
            const uint32_t c0 = ((uint32_t)t        < C) ? list[t]       : 0u;
            const uint32_t c1 = ((uint32_t)t + 64u  < C) ? list[t + 64]  : 0u;
            const uint32_t c2 = ((uint32_t)t + 128u < C) ? list[t + 128] : 0u;
            const uint32_t c3 = ((uint32_t)t + 192u < C) ? list[t + 192] : 0u;
            uint32_t prefix = 0, kk = KSEL;
            for (int b = 30; b >= 0; --b) {
                const uint32_t want = prefix | (1u << b);      // pad 0 never matches
                const uint32_t mhi  = ~((1u << b) - 1u);
                const uint64_t m0 = __ballot((c0 & mhi) == want);
                const uint64_t m1 = __ballot((c1 & mhi) == want);
                const uint64_t m2 = __ballot((c2 & mhi) == want);
                const uint64_t m3 = __ballot((c3 & mhi) == want);
                const uint32_t cc = (uint32_t)(__popcll(m0) + __popcll(m1) +
                                               __popcll(m2) + __popcll(m3));
                if (cc >= kk) prefix = want; else kk -= cc;
            }
            // 64th largest = min of candidates strictly > prefix (if exactly 64)
            const uint32_t cgt = (uint32_t)(__popcll(__ballot(c0 > prefix)) +
                                            __popcll(__ballot(c1 > prefix)) +
                                            __popcll(__ballot(c2 > prefix)) +
                                            __popcll(__ballot(c3 > prefix)));
            uint32_t mnl = 0xFFFFFFFFu;
            if (c0 > prefix) mnl = min(mnl, c0);
            if (c1 > prefix) mnl = min(mnl, c1);
            if (c2 > prefix) mnl = min(mnl, c2);
            if (c3 > prefix) mnl = min(mnl, c3);
#pragma unroll
            for (int off = 32; off >= 1; off >>= 1)
                mnl = min(mnl, (uint32_t)__shfl_xor(mnl, off, 64));
            if (t == 0) {
                const float v65 = __uint_as_float(prefix);
                const float v64 = (cgt == 64u) ? __uint_as_float(mnl) : v65;
                // Q = v65 + frac*(v64 - v65), frac = 1/64 (exact in binary)
                q_sh = fmaf(0.015625f, v64 - v65, v65);
            }
        }
        __syncthreads();
    } else {
        __syncthreads();   // match the fast path's post-compaction barrier
        // Fallback (adversarial data only): exact block-wide bitwise select.
        uint32_t prefix = 0, kk = KSEL;
        for (int b = 30; b >= 0; --b) {
            const uint32_t want = prefix | (1u << b);
            const uint32_t mhi  = ~((1u << b) - 1u);
            uint32_t c = 0;
#pragma unroll
            for (int i = 0; i < EPT; ++i) c += ((a[i] & mhi) == want) ? 1u : 0u;
#pragma unroll
            for (int off2 = 32; off2 >= 1; off2 >>= 1) c += __shfl_down(c, off2, 64);
            if (lane == 0) wcnt[wave] = c;
            __syncthreads();
            const uint32_t tot = wcnt[0] + wcnt[1] + wcnt[2] + wcnt[3];
            if (tot >= kk) prefix = want; else kk -= tot;
            __syncthreads();
        }
        // 64th largest: block-wide min/count of elements strictly > prefix
        uint32_t cgt = 0, mn = 0xFFFFFFFFu;
#pragma unroll
        for (int i = 0; i < EPT; ++i) {
            if (a[i] > prefix) { cgt++; mn = min(mn, a[i]); }
        }
#pragma unroll
        for (int off2 = 32; off2 >= 1; off2 >>= 1) {
            cgt += __shfl_down(cgt, off2, 64);
            const uint32_t m2 = __shfl_down(mn, off2, 64);
            mn = min(mn, m2);
        }
        if (lane == 0) { wcnt[wave] = cgt; wmn[wave] = mn; }
        __syncthreads();
        if (t == 0) {
            const uint32_t Ct = wcnt[0] + wcnt[1] + wcnt[2] + wcnt[3];
            const uint32_t M  = min(min(wmn[0], wmn[1]), min(wmn[2], wmn[3]));
            const float v65 = __uint_as_float(prefix);
            const float v64 = (Ct == 64u) ? __uint_as_float(M) : v65;
            q_sh = fmaf(0.015625f, v64 - v65, v65);
        }
        __syncthreads();
    }
    const float Q = q_sh;

    // ---- Epilogue: r = max(|x| - Q, 0); OR the saved sign bit back in
    // (r >= 0, so pattern-OR == copysignf, including the -0.0 cases).
    f32x4* __restrict__ o4 = reinterpret_cast<f32x4*>(out + (size_t)row * NCOLS);
#pragma unroll
    for (int i = 0; i < 4; ++i) {
        f32x4 f;
#pragma unroll
        for (int j = 0; j < 4; ++j) {
            const int e = 4 * i + j;
            const float r = fmaxf(__uint_as_float(a[e]) - Q, 0.0f);
            const uint32_t sp = __float_as_uint(r) | ((smask << (31 - e)) & 0x80000000u);
            f[j] = __uint_as_float(sp);
        }
        __builtin_nontemporal_store(f, o4 + t + THREADS * i);
    }
}

extern "C" void kernel_launch(void* const* d_in, const int* in_sizes, int n_in,
                              void* d_out, int out_size, void* d_ws, size_t ws_size,
                              hipStream_t stream) {
    const float* X   = (const float*)d_in[0];
    float*       out = (float*)d_out;
    const int rows = in_sizes[0] / NCOLS;   // 16384
    topk_sparsify<<<rows, THREADS, 0, stream>>>(X, out, rows);
}